// Round 1
// baseline (103.720 us; speedup 1.0000x reference)
//
#include <hip/hip_runtime.h>
#include <math.h>

#define DIM   100
#define MAX_S 201      // int(DIM/0.5) + 1
#define NV    64
#define BS    512

// ---------------------------------------------------------------------------
// Kernel 1: one block per (batch, direction m). Stages gt_mask[b][m] in LDS,
// computes s_m = sum over edges of sign*(sf+sb)*0.5, writes |s_m| to ws[b*4+m].
// ---------------------------------------------------------------------------
__global__ __launch_bounds__(256) void diffiou_intersect(
    const float* __restrict__ poly, const float* __restrict__ gt_mask,
    float* __restrict__ ws) {
  __shared__ float smask[DIM * DIM];       // 40000 B
  __shared__ float prm[128][9];            // per-combo params
  __shared__ float red[4];

  const int bid = blockIdx.x;
  const int b   = bid >> 2;
  const int m   = bid & 3;
  const bool ax = (m < 2);                 // DIRECTIONS = x,x,y,y
  const int tid = threadIdx.x;

  // ---- stage mask slice into LDS (float4 coalesced) ----
  {
    const float4* src = reinterpret_cast<const float4*>(
        gt_mask + (size_t)(b * 4 + m) * (DIM * DIM));
    float4* dst = reinterpret_cast<float4*>(smask);
    #pragma unroll 4
    for (int j = tid; j < DIM * DIM / 4; j += 256) dst[j] = src[j];
  }

  // ---- per-combo edge params: combo c = e*2 + fb ----
  if (tid < 128) {
    const int e  = tid >> 1;
    const int fb = tid & 1;
    const float* pb = poly + (size_t)b * NV * 2;
    const float ex0 = pb[e * 2 + 0], ey0 = pb[e * 2 + 1];
    const int   en  = (e + 1) & (NV - 1);
    const float ex1 = pb[en * 2 + 0], ey1 = pb[en * 2 + 1];
    // sign from FORWARD orientation regardless of fb
    const float sign = (ax ? (ex1 > ex0) : (ey1 > ey0)) ? 1.0f : -1.0f;
    const float x0 = fb ? ex1 : ex0, y0 = fb ? ey1 : ey0;
    const float x1 = fb ? ex0 : ex1, y1 = fb ? ey0 : ey1;
    float vx = (x1 - x0) + 1e-6f;          // matches ref rounding (no fma risk)
    float vy = (y1 - y0) + 1e-6f;
    const float n = __fsqrt_rn(__fadd_rn(__fmul_rn(vx, vx), __fmul_rn(vy, vy)));
    vx = __fdiv_rn(vx, n);
    vy = __fdiv_rn(vy, n);
    const float xlo = fminf(x0, x1), xhi = fmaxf(x0, x1);
    const float ylo = fminf(y0, y1), yhi = fmaxf(y0, y1);
    prm[tid][0] = x0;            prm[tid][1] = y0;
    prm[tid][2] = vx;            prm[tid][3] = vy;
    prm[tid][4] = xlo - 0.001f;  prm[tid][5] = xhi + 0.001f;
    prm[tid][6] = ylo - 0.001f;  prm[tid][7] = yhi + 0.001f;
    prm[tid][8] = sign * 0.5f;
  }
  __syncthreads();

  float acc = 0.0f;
  const int TOT = 128 * MAX_S;
  for (int i = tid; i < TOT; i += 256) {
    const int c = i / MAX_S;               // consecutive lanes: same combo, t+1
    const int t = i - c * MAX_S;

    const float x0  = prm[c][0], y0  = prm[c][1];
    const float vx  = prm[c][2], vy  = prm[c][3];
    const float xlo = prm[c][4], xhi = prm[c][5];
    const float ylo = prm[c][6], yhi = prm[c][7];

    const float tf = (float)t;
    // exact ref rounding: (t*vx) rounded, then + x0 rounded (no fma)
    const float xs = __fadd_rn(__fmul_rn(tf, vx), x0);
    const float ys = __fadd_rn(__fmul_rn(tf, vy), y0);
    bool valid = (xs <= xhi) && (xs >= xlo) && (ys <= yhi) && (ys >= ylo);
    const float u = ax ? xs : ys;
    valid = valid && (u <= (float)(DIM - 1)) && (u >= 0.0f);
    if (!valid) continue;

    bool keep;
    if (t == 0) {
      keep = true;                         // first==valid -> keep==valid
    } else {
      const float tp = tf - 1.0f;
      const float xp = __fadd_rn(__fmul_rn(tp, vx), x0);
      const float yp = __fadd_rn(__fmul_rn(tp, vy), y0);
      bool pv = (xp <= xhi) && (xp >= xlo) && (yp <= yhi) && (yp >= ylo);
      const float up = ax ? xp : yp;
      pv = pv && (up <= (float)(DIM - 1)) && (up >= 0.0f);
      keep = (!pv) || (floorf(u) != floorf(up));
    }
    if (!keep) continue;

    const float X0 = floorf(xs), Y0 = floorf(ys);
    const float wx1 = xs - X0;
    const float wx0 = (X0 + 1.0f) - xs;
    const float wy1 = ys - Y0;
    const float wy0 = (Y0 + 1.0f) - ys;
    const int xi0 = min(max((int)X0, 0), DIM - 1);
    const int xi1 = min(max((int)(X0 + 1.0f), 0), DIM - 1);
    const int yi0 = min(max((int)Y0, 0), DIM - 1);
    const int yi1 = min(max((int)(Y0 + 1.0f), 0), DIM - 1);
    const float g00 = smask[yi0 * DIM + xi0];
    const float g01 = smask[yi1 * DIM + xi0];
    const float g10 = smask[yi0 * DIM + xi1];
    const float g11 = smask[yi1 * DIM + xi1];
    const float val = wx0 * wy0 * g00 + wx0 * wy1 * g01 +
                      wx1 * wy0 * g10 + wx1 * wy1 * g11;
    acc += prm[c][8] * val;                // sign*0.5*val
  }

  // ---- block reduce (4 waves) ----
  #pragma unroll
  for (int o = 32; o > 0; o >>= 1) acc += __shfl_xor(acc, o, 64);
  if ((tid & 63) == 0) red[tid >> 6] = acc;
  __syncthreads();
  if (tid == 0) {
    const float s = red[0] + red[1] + red[2] + red[3];
    ws[bid] = fabsf(s);
  }
}

// ---------------------------------------------------------------------------
// Kernel 2: per-batch areas + final IoU. One wave per batch.
// ---------------------------------------------------------------------------
__device__ __forceinline__ float wave_area(const float* P, int b, int v) {
  const float x0 = P[(size_t)(b * NV + v) * 2 + 0];
  const float y0 = P[(size_t)(b * NV + v) * 2 + 1];
  const int vn = (v + 1) & (NV - 1);
  const float x1 = P[(size_t)(b * NV + vn) * 2 + 0];
  const float y1 = P[(size_t)(b * NV + vn) * 2 + 1];
  float ym = y0;
  #pragma unroll
  for (int o = 32; o > 0; o >>= 1) ym = fmaxf(ym, __shfl_xor(ym, o, 64));
  float term = (x1 - x0) * (ym - (y1 + y0) * 0.5f);
  #pragma unroll
  for (int o = 32; o > 0; o >>= 1) term += __shfl_xor(term, o, 64);
  return fabsf(term);
}

__global__ __launch_bounds__(64) void diffiou_finalize(
    const float* __restrict__ poly, const float* __restrict__ gt,
    const float* __restrict__ ws, float* __restrict__ out) {
  const int b = blockIdx.x;
  const int v = threadIdx.x;
  const float pa = wave_area(poly, b, v);
  const float ga = wave_area(gt, b, v);
  if (v == 0) {
    const float ia = 0.25f * (ws[b * 4 + 0] + ws[b * 4 + 1] +
                              ws[b * 4 + 2] + ws[b * 4 + 3]);
    out[b] = ia / (pa + ga - ia);
  }
}

// ---------------------------------------------------------------------------
extern "C" void kernel_launch(void* const* d_in, const int* in_sizes, int n_in,
                              void* d_out, int out_size, void* d_ws, size_t ws_size,
                              hipStream_t stream) {
  const float* poly    = (const float*)d_in[0];
  const float* gt      = (const float*)d_in[1];
  const float* gt_mask = (const float*)d_in[2];
  float* out = (float*)d_out;
  float* ws  = (float*)d_ws;   // 2048 floats: |s| per (batch, direction)

  hipLaunchKernelGGL(diffiou_intersect, dim3(BS * 4), dim3(256), 0, stream,
                     poly, gt_mask, ws);
  hipLaunchKernelGGL(diffiou_finalize, dim3(BS), dim3(64), 0, stream,
                     poly, gt, ws, out);
}

// Round 2
// 52.611 us; speedup vs baseline: 1.9715x; 1.9715x over previous
//
#include <hip/hip_runtime.h>
#include <math.h>

#define DIM   100
#define MAX_S 201      // int(DIM/0.5) + 1
#define NV    64
#define BS    512

// ---------------------------------------------------------------------------
// Kernel 1: one block per (batch, direction m). Stages gt_mask[b][m] in LDS.
// 4 waves/block; each wave handles 16 edges; within a wave, lanes 0-31 run
// the forward line, lanes 32-63 the backward line, 32 steps per chunk.
// Validity is contiguous from t=0 (proof: all constraints hold at t=0 and are
// float-monotone in t), so we iterate only to a conservative analytic t_end
// and keep = valid && (t==0 || floor(u) != floor(u_prev)).
// ---------------------------------------------------------------------------
__global__ __launch_bounds__(256) void diffiou_intersect(
    const float* __restrict__ poly, const float* __restrict__ gt_mask,
    float* __restrict__ ws) {
  __shared__ float smask[DIM * DIM];       // 40000 B
  __shared__ float prm[128][9];            // per-combo params
  __shared__ int   tend[128];              // conservative step count
  __shared__ float red[4];

  const int bid = blockIdx.x;
  const int b   = bid >> 2;
  const int m   = bid & 3;
  const bool ax = (m < 2);                 // DIRECTIONS = x,x,y,y
  const int tid = threadIdx.x;

  // ---- stage mask slice into LDS (float4 coalesced) ----
  {
    const float4* src = reinterpret_cast<const float4*>(
        gt_mask + (size_t)(b * 4 + m) * (DIM * DIM));
    float4* dst = reinterpret_cast<float4*>(smask);
    #pragma unroll 4
    for (int j = tid; j < DIM * DIM / 4; j += 256) dst[j] = src[j];
  }

  // ---- per-combo edge params: combo c = e*2 + fb ----
  if (tid < 128) {
    const int e  = tid >> 1;
    const int fb = tid & 1;
    const float* pb = poly + (size_t)b * NV * 2;
    const float ex0 = pb[e * 2 + 0], ey0 = pb[e * 2 + 1];
    const int   en  = (e + 1) & (NV - 1);
    const float ex1 = pb[en * 2 + 0], ey1 = pb[en * 2 + 1];
    // sign from FORWARD orientation regardless of fb
    const float sign = (ax ? (ex1 > ex0) : (ey1 > ey0)) ? 1.0f : -1.0f;
    const float x0 = fb ? ex1 : ex0, y0 = fb ? ey1 : ey0;
    const float x1 = fb ? ex0 : ex1, y1 = fb ? ey0 : ey1;
    float vx = (x1 - x0) + 1e-6f;          // matches ref rounding (no fma)
    float vy = (y1 - y0) + 1e-6f;
    const float n = __fsqrt_rn(__fadd_rn(__fmul_rn(vx, vx), __fmul_rn(vy, vy)));
    vx = __fdiv_rn(vx, n);
    vy = __fdiv_rn(vy, n);
    const float xlo = fminf(x0, x1) - 0.001f, xhi = fmaxf(x0, x1) + 0.001f;
    const float ylo = fminf(y0, y1) - 0.001f, yhi = fmaxf(y0, y1) + 0.001f;
    prm[tid][0] = x0;   prm[tid][1] = y0;
    prm[tid][2] = vx;   prm[tid][3] = vy;
    prm[tid][4] = xlo;  prm[tid][5] = xhi;
    prm[tid][6] = ylo;  prm[tid][7] = yhi;
    prm[tid][8] = sign * 0.5f;

    // conservative last-valid-t bound (+2 margin, exact check done inside)
    float tmax = 200.0f;
    if (vx > 0.0f) tmax = fminf(tmax, (xhi - x0) / vx);
    else if (vx < 0.0f) tmax = fminf(tmax, (xlo - x0) / vx);
    if (vy > 0.0f) tmax = fminf(tmax, (yhi - y0) / vy);
    else if (vy < 0.0f) tmax = fminf(tmax, (ylo - y0) / vy);
    const float vu = ax ? vx : vy;
    const float u0 = ax ? x0 : y0;
    if (vu > 0.0f) tmax = fminf(tmax, ((float)(DIM - 1) - u0) / vu);
    else if (vu < 0.0f) tmax = fminf(tmax, -u0 / vu);
    int te = (int)floorf(tmax) + 3;        // count of steps to examine
    te = max(1, min(te, MAX_S));
    tend[tid] = te;
  }
  __syncthreads();

  const int wid  = tid >> 6;
  const int lane = tid & 63;
  const int half = lane >> 5;              // 0 = fwd, 1 = bwd
  const int sl   = lane & 31;

  float acc = 0.0f;
  for (int k = 0; k < 16; ++k) {
    const int e = wid * 16 + k;
    const int c = e * 2 + half;
    const float x0  = prm[c][0], y0  = prm[c][1];
    const float vx  = prm[c][2], vy  = prm[c][3];
    const float xlo = prm[c][4], xhi = prm[c][5];
    const float ylo = prm[c][6], yhi = prm[c][7];
    const float shw = prm[c][8];
    const float vu = ax ? vx : vy;
    const float u0 = ax ? x0 : y0;
    const int te    = tend[c];
    const int teMax = max(tend[e * 2], tend[e * 2 + 1]);

    for (int t0 = 0; t0 < teMax; t0 += 32) {
      const int t = t0 + sl;
      const float tf = (float)t;
      // exact ref rounding: (t*v) rounded, then + p0 rounded (no fma)
      const float xs = __fadd_rn(__fmul_rn(tf, vx), x0);
      const float ys = __fadd_rn(__fmul_rn(tf, vy), y0);
      const float u  = ax ? xs : ys;
      const float fu = floorf(u);
      // prev floor(u): exact same expression as lane sl-1's fu
      float fup = __shfl_up(fu, 1, 32);
      if (sl == 0 && t0 > 0) {
        const float up = __fadd_rn(__fmul_rn((float)(t - 1), vu), u0);
        fup = floorf(up);
      }
      bool valid = (t < te) &&
                   (xs <= xhi) && (xs >= xlo) && (ys <= yhi) && (ys >= ylo) &&
                   (u <= (float)(DIM - 1)) && (u >= 0.0f);
      const bool keep = valid && ((t == 0) || (fu != fup));
      if (!keep) continue;

      const float X0 = floorf(xs), Y0 = floorf(ys);
      const float wx1 = xs - X0;
      const float wx0 = (X0 + 1.0f) - xs;
      const float wy1 = ys - Y0;
      const float wy0 = (Y0 + 1.0f) - ys;
      const int xi0 = min(max((int)X0, 0), DIM - 1);
      const int xi1 = min(max((int)(X0 + 1.0f), 0), DIM - 1);
      const int yi0 = min(max((int)Y0, 0), DIM - 1);
      const int yi1 = min(max((int)(Y0 + 1.0f), 0), DIM - 1);
      const float g00 = smask[yi0 * DIM + xi0];
      const float g01 = smask[yi1 * DIM + xi0];
      const float g10 = smask[yi0 * DIM + xi1];
      const float g11 = smask[yi1 * DIM + xi1];
      const float val = wx0 * wy0 * g00 + wx0 * wy1 * g01 +
                        wx1 * wy0 * g10 + wx1 * wy1 * g11;
      acc += shw * val;                    // sign*0.5*val
    }
  }

  // ---- block reduce (4 waves) ----
  #pragma unroll
  for (int o = 32; o > 0; o >>= 1) acc += __shfl_xor(acc, o, 64);
  if ((tid & 63) == 0) red[tid >> 6] = acc;
  __syncthreads();
  if (tid == 0) {
    const float s = red[0] + red[1] + red[2] + red[3];
    ws[bid] = fabsf(s);
  }
}

// ---------------------------------------------------------------------------
// Kernel 2: per-batch areas + final IoU. One wave per batch.
// ---------------------------------------------------------------------------
__device__ __forceinline__ float wave_area(const float* P, int b, int v) {
  const float x0 = P[(size_t)(b * NV + v) * 2 + 0];
  const float y0 = P[(size_t)(b * NV + v) * 2 + 1];
  const int vn = (v + 1) & (NV - 1);
  const float x1 = P[(size_t)(b * NV + vn) * 2 + 0];
  const float y1 = P[(size_t)(b * NV + vn) * 2 + 1];
  float ym = y0;
  #pragma unroll
  for (int o = 32; o > 0; o >>= 1) ym = fmaxf(ym, __shfl_xor(ym, o, 64));
  float term = (x1 - x0) * (ym - (y1 + y0) * 0.5f);
  #pragma unroll
  for (int o = 32; o > 0; o >>= 1) term += __shfl_xor(term, o, 64);
  return fabsf(term);
}

__global__ __launch_bounds__(64) void diffiou_finalize(
    const float* __restrict__ poly, const float* __restrict__ gt,
    const float* __restrict__ ws, float* __restrict__ out) {
  const int b = blockIdx.x;
  const int v = threadIdx.x;
  const float pa = wave_area(poly, b, v);
  const float ga = wave_area(gt, b, v);
  if (v == 0) {
    const float ia = 0.25f * (ws[b * 4 + 0] + ws[b * 4 + 1] +
                              ws[b * 4 + 2] + ws[b * 4 + 3]);
    out[b] = ia / (pa + ga - ia);
  }
}

// ---------------------------------------------------------------------------
extern "C" void kernel_launch(void* const* d_in, const int* in_sizes, int n_in,
                              void* d_out, int out_size, void* d_ws, size_t ws_size,
                              hipStream_t stream) {
  const float* poly    = (const float*)d_in[0];
  const float* gt      = (const float*)d_in[1];
  const float* gt_mask = (const float*)d_in[2];
  float* out = (float*)d_out;
  float* ws  = (float*)d_ws;   // 2048 floats: |s| per (batch, direction)

  hipLaunchKernelGGL(diffiou_intersect, dim3(BS * 4), dim3(256), 0, stream,
                     poly, gt_mask, ws);
  hipLaunchKernelGGL(diffiou_finalize, dim3(BS), dim3(64), 0, stream,
                     poly, gt, ws, out);
}

// Round 3
// 47.692 us; speedup vs baseline: 2.1748x; 1.1031x over previous
//
#include <hip/hip_runtime.h>
#include <math.h>

#define DIM   100
#define MAX_S 201      // int(DIM/0.5) + 1
#define NV    64
#define BS    512

typedef _Float16 half4v __attribute__((ext_vector_type(4)));

// ---------------------------------------------------------------------------
// Kernel 1: one block per (batch, direction m). Stages gt_mask[b][m] in LDS
// as fp16 (20 KB -> 6 blocks/CU instead of 3). 4 waves/block; each wave
// handles 16 edges; lanes 0-31 run the forward line, lanes 32-63 backward.
// Validity is contiguous from t=0 (all constraints hold at t=0 and are
// float-monotone in t), so we iterate only to a conservative analytic t_end
// and keep = valid && (t==0 || floor(u) != floor(u_prev)).
// fp16 mask error budget: rel 2^-11 per sample -> ~1e-5 on the final iou,
// vs 2.26e-3 threshold.
// ---------------------------------------------------------------------------
__global__ __launch_bounds__(256) void diffiou_intersect(
    const float* __restrict__ poly, const float* __restrict__ gt_mask,
    float* __restrict__ ws) {
  __shared__ _Float16 smask[DIM * DIM];    // 20000 B
  __shared__ float prm[128][9];            // per-combo params (4608 B)
  __shared__ int   tend[128];              // conservative step count
  __shared__ float red[4];

  const int bid = blockIdx.x;
  const int b   = bid >> 2;
  const int m   = bid & 3;
  const bool ax = (m < 2);                 // DIRECTIONS = x,x,y,y
  const int tid = threadIdx.x;

  // ---- stage mask slice into LDS, fp32 -> fp16 ----
  {
    const float4* src = reinterpret_cast<const float4*>(
        gt_mask + (size_t)(b * 4 + m) * (DIM * DIM));
    #pragma unroll 5
    for (int j = tid; j < DIM * DIM / 4; j += 256) {
      const float4 v = src[j];
      half4v h;
      h.x = (_Float16)v.x; h.y = (_Float16)v.y;
      h.z = (_Float16)v.z; h.w = (_Float16)v.w;
      *reinterpret_cast<half4v*>(&smask[j * 4]) = h;   // 8B-aligned
    }
  }

  // ---- per-combo edge params: combo c = e*2 + fb ----
  if (tid < 128) {
    const int e  = tid >> 1;
    const int fb = tid & 1;
    const float* pb = poly + (size_t)b * NV * 2;
    const float ex0 = pb[e * 2 + 0], ey0 = pb[e * 2 + 1];
    const int   en  = (e + 1) & (NV - 1);
    const float ex1 = pb[en * 2 + 0], ey1 = pb[en * 2 + 1];
    // sign from FORWARD orientation regardless of fb
    const float sign = (ax ? (ex1 > ex0) : (ey1 > ey0)) ? 1.0f : -1.0f;
    const float x0 = fb ? ex1 : ex0, y0 = fb ? ey1 : ey0;
    const float x1 = fb ? ex0 : ex1, y1 = fb ? ey0 : ey1;
    float vx = (x1 - x0) + 1e-6f;          // matches ref rounding (no fma)
    float vy = (y1 - y0) + 1e-6f;
    const float n = __fsqrt_rn(__fadd_rn(__fmul_rn(vx, vx), __fmul_rn(vy, vy)));
    vx = __fdiv_rn(vx, n);
    vy = __fdiv_rn(vy, n);
    const float xlo = fminf(x0, x1) - 0.001f, xhi = fmaxf(x0, x1) + 0.001f;
    const float ylo = fminf(y0, y1) - 0.001f, yhi = fmaxf(y0, y1) + 0.001f;
    prm[tid][0] = x0;   prm[tid][1] = y0;
    prm[tid][2] = vx;   prm[tid][3] = vy;
    prm[tid][4] = xlo;  prm[tid][5] = xhi;
    prm[tid][6] = ylo;  prm[tid][7] = yhi;
    prm[tid][8] = sign * 0.5f;

    // conservative last-valid-t bound (+2 margin, exact check done inside)
    float tmax = 200.0f;
    if (vx > 0.0f) tmax = fminf(tmax, (xhi - x0) / vx);
    else if (vx < 0.0f) tmax = fminf(tmax, (xlo - x0) / vx);
    if (vy > 0.0f) tmax = fminf(tmax, (yhi - y0) / vy);
    else if (vy < 0.0f) tmax = fminf(tmax, (ylo - y0) / vy);
    const float vu = ax ? vx : vy;
    const float u0 = ax ? x0 : y0;
    if (vu > 0.0f) tmax = fminf(tmax, ((float)(DIM - 1) - u0) / vu);
    else if (vu < 0.0f) tmax = fminf(tmax, -u0 / vu);
    int te = (int)floorf(tmax) + 3;        // count of steps to examine
    te = max(1, min(te, MAX_S));
    tend[tid] = te;
  }
  __syncthreads();

  const int wid  = tid >> 6;
  const int lane = tid & 63;
  const int half = lane >> 5;              // 0 = fwd, 1 = bwd
  const int sl   = lane & 31;

  float acc = 0.0f;
  for (int k = 0; k < 16; ++k) {
    const int e = wid * 16 + k;
    const int c = e * 2 + half;
    const float x0  = prm[c][0], y0  = prm[c][1];
    const float vx  = prm[c][2], vy  = prm[c][3];
    const float xlo = prm[c][4], xhi = prm[c][5];
    const float ylo = prm[c][6], yhi = prm[c][7];
    const float shw = prm[c][8];
    const float vu = ax ? vx : vy;
    const float u0 = ax ? x0 : y0;
    const int te    = tend[c];
    const int teMax = max(tend[e * 2], tend[e * 2 + 1]);

    for (int t0 = 0; t0 < teMax; t0 += 32) {
      const int t = t0 + sl;
      const float tf = (float)t;
      // exact ref rounding: (t*v) rounded, then + p0 rounded (no fma)
      const float xs = __fadd_rn(__fmul_rn(tf, vx), x0);
      const float ys = __fadd_rn(__fmul_rn(tf, vy), y0);
      const float u  = ax ? xs : ys;
      const float fu = floorf(u);
      // prev floor(u): exact same expression as lane sl-1's fu
      float fup = __shfl_up(fu, 1, 32);
      if (sl == 0 && t0 > 0) {
        const float up = __fadd_rn(__fmul_rn((float)(t - 1), vu), u0);
        fup = floorf(up);
      }
      bool valid = (t < te) &&
                   (xs <= xhi) && (xs >= xlo) && (ys <= yhi) && (ys >= ylo) &&
                   (u <= (float)(DIM - 1)) && (u >= 0.0f);
      const bool keep = valid && ((t == 0) || (fu != fup));
      if (!keep) continue;

      const float X0 = floorf(xs), Y0 = floorf(ys);
      const float wx1 = xs - X0;
      const float wx0 = (X0 + 1.0f) - xs;
      const float wy1 = ys - Y0;
      const float wy0 = (Y0 + 1.0f) - ys;
      const int xi0 = min(max((int)X0, 0), DIM - 1);
      const int xi1 = min(max((int)(X0 + 1.0f), 0), DIM - 1);
      const int yi0 = min(max((int)Y0, 0), DIM - 1);
      const int yi1 = min(max((int)Y0, 0), DIM - 1) * 0 + min(max((int)(Y0 + 1.0f), 0), DIM - 1);
      const float g00 = (float)smask[yi0 * DIM + xi0];
      const float g01 = (float)smask[yi1 * DIM + xi0];
      const float g10 = (float)smask[yi0 * DIM + xi1];
      const float g11 = (float)smask[yi1 * DIM + xi1];
      const float val = wx0 * wy0 * g00 + wx0 * wy1 * g01 +
                        wx1 * wy0 * g10 + wx1 * wy1 * g11;
      acc += shw * val;                    // sign*0.5*val
    }
  }

  // ---- block reduce (4 waves) ----
  #pragma unroll
  for (int o = 32; o > 0; o >>= 1) acc += __shfl_xor(acc, o, 64);
  if ((tid & 63) == 0) red[tid >> 6] = acc;
  __syncthreads();
  if (tid == 0) {
    const float s = red[0] + red[1] + red[2] + red[3];
    ws[bid] = fabsf(s);
  }
}

// ---------------------------------------------------------------------------
// Kernel 2: per-batch areas + final IoU. One wave per batch.
// ---------------------------------------------------------------------------
__device__ __forceinline__ float wave_area(const float* P, int b, int v) {
  const float x0 = P[(size_t)(b * NV + v) * 2 + 0];
  const float y0 = P[(size_t)(b * NV + v) * 2 + 1];
  const int vn = (v + 1) & (NV - 1);
  const float x1 = P[(size_t)(b * NV + vn) * 2 + 0];
  const float y1 = P[(size_t)(b * NV + vn) * 2 + 1];
  float ym = y0;
  #pragma unroll
  for (int o = 32; o > 0; o >>= 1) ym = fmaxf(ym, __shfl_xor(ym, o, 64));
  float term = (x1 - x0) * (ym - (y1 + y0) * 0.5f);
  #pragma unroll
  for (int o = 32; o > 0; o >>= 1) term += __shfl_xor(term, o, 64);
  return fabsf(term);
}

__global__ __launch_bounds__(64) void diffiou_finalize(
    const float* __restrict__ poly, const float* __restrict__ gt,
    const float* __restrict__ ws, float* __restrict__ out) {
  const int b = blockIdx.x;
  const int v = threadIdx.x;
  const float pa = wave_area(poly, b, v);
  const float ga = wave_area(gt, b, v);
  if (v == 0) {
    const float ia = 0.25f * (ws[b * 4 + 0] + ws[b * 4 + 1] +
                              ws[b * 4 + 2] + ws[b * 4 + 3]);
    out[b] = ia / (pa + ga - ia);
  }
}

// ---------------------------------------------------------------------------
extern "C" void kernel_launch(void* const* d_in, const int* in_sizes, int n_in,
                              void* d_out, int out_size, void* d_ws, size_t ws_size,
                              hipStream_t stream) {
  const float* poly    = (const float*)d_in[0];
  const float* gt      = (const float*)d_in[1];
  const float* gt_mask = (const float*)d_in[2];
  float* out = (float*)d_out;
  float* ws  = (float*)d_ws;   // 2048 floats: |s| per (batch, direction)

  hipLaunchKernelGGL(diffiou_intersect, dim3(BS * 4), dim3(256), 0, stream,
                     poly, gt_mask, ws);
  hipLaunchKernelGGL(diffiou_finalize, dim3(BS), dim3(64), 0, stream,
                     poly, gt, ws, out);
}

// Round 4
// 46.931 us; speedup vs baseline: 2.2100x; 1.0162x over previous
//
#include <hip/hip_runtime.h>
#include <math.h>

#define DIM   100
#define MAX_S 201      // int(DIM/0.5) + 1
#define NV    64
#define BS    512

// ---------------------------------------------------------------------------
// Kernel 1: one block per (batch, direction m). Stages gt_mask[b][m] in LDS
// as u8 (10 KB; total LDS ~15.1 KB -> 8 blocks/CU, and 8*256 = 2048 = grid,
// so the WHOLE grid is co-resident: no residency tail). 4 waves/block; each
// wave handles 16 edges; lanes 0-31 forward line, lanes 32-63 backward.
// Validity is contiguous from t=0 (all constraints hold at t=0 and are
// float-monotone in t), so we iterate to a conservative analytic t_end;
// keep = valid && (t==0 || floor(u) != floor(u_prev)), with u_prev's floor
// recomputed directly (3 VALU) instead of shfl (LDS-pipe latency stall).
// u8 mask error budget: eps<=1/510/sample -> ~1e-5 on iou vs 2.26e-3 thr.
// ---------------------------------------------------------------------------
__global__ __launch_bounds__(256, 8) void diffiou_intersect(
    const float* __restrict__ poly, const float* __restrict__ gt_mask,
    float* __restrict__ ws) {
  __shared__ unsigned char smask[DIM * DIM];  // 10000 B
  __shared__ float prm[128][9];               // per-combo params (4608 B)
  __shared__ int   tend[128];                 // conservative step count
  __shared__ float red[4];

  const int bid = blockIdx.x;
  const int b   = bid >> 2;
  const int m   = bid & 3;
  const bool ax = (m < 2);                 // DIRECTIONS = x,x,y,y
  const int tid = threadIdx.x;

  // ---- stage mask slice into LDS, fp32 -> u8 (x255, RNE) ----
  {
    const float4* src = reinterpret_cast<const float4*>(
        gt_mask + (size_t)(b * 4 + m) * (DIM * DIM));
    #pragma unroll 5
    for (int j = tid; j < DIM * DIM / 4; j += 256) {
      const float4 v = src[j];
      uchar4 c;
      c.x = (unsigned char)__float2int_rn(v.x * 255.0f);
      c.y = (unsigned char)__float2int_rn(v.y * 255.0f);
      c.z = (unsigned char)__float2int_rn(v.z * 255.0f);
      c.w = (unsigned char)__float2int_rn(v.w * 255.0f);
      *reinterpret_cast<uchar4*>(&smask[j * 4]) = c;    // 4B-aligned
    }
  }

  // ---- per-combo edge params: combo c = e*2 + fb ----
  if (tid < 128) {
    const int e  = tid >> 1;
    const int fb = tid & 1;
    const float* pb = poly + (size_t)b * NV * 2;
    const float ex0 = pb[e * 2 + 0], ey0 = pb[e * 2 + 1];
    const int   en  = (e + 1) & (NV - 1);
    const float ex1 = pb[en * 2 + 0], ey1 = pb[en * 2 + 1];
    // sign from FORWARD orientation regardless of fb
    const float sign = (ax ? (ex1 > ex0) : (ey1 > ey0)) ? 1.0f : -1.0f;
    const float x0 = fb ? ex1 : ex0, y0 = fb ? ey1 : ey0;
    const float x1 = fb ? ex0 : ex1, y1 = fb ? ey0 : ey1;
    float vx = (x1 - x0) + 1e-6f;          // matches ref rounding (no fma)
    float vy = (y1 - y0) + 1e-6f;
    const float n = __fsqrt_rn(__fadd_rn(__fmul_rn(vx, vx), __fmul_rn(vy, vy)));
    vx = __fdiv_rn(vx, n);
    vy = __fdiv_rn(vy, n);
    const float xlo = fminf(x0, x1) - 0.001f, xhi = fmaxf(x0, x1) + 0.001f;
    const float ylo = fminf(y0, y1) - 0.001f, yhi = fmaxf(y0, y1) + 0.001f;
    prm[tid][0] = x0;   prm[tid][1] = y0;
    prm[tid][2] = vx;   prm[tid][3] = vy;
    prm[tid][4] = xlo;  prm[tid][5] = xhi;
    prm[tid][6] = ylo;  prm[tid][7] = yhi;
    prm[tid][8] = sign * (0.5f / 255.0f);  // fold u8 dequant into weight

    // conservative last-valid-t bound (+2 margin, exact check done inside)
    float tmax = 200.0f;
    if (vx > 0.0f) tmax = fminf(tmax, (xhi - x0) / vx);
    else if (vx < 0.0f) tmax = fminf(tmax, (xlo - x0) / vx);
    if (vy > 0.0f) tmax = fminf(tmax, (yhi - y0) / vy);
    else if (vy < 0.0f) tmax = fminf(tmax, (ylo - y0) / vy);
    const float vu = ax ? vx : vy;
    const float u0 = ax ? x0 : y0;
    if (vu > 0.0f) tmax = fminf(tmax, ((float)(DIM - 1) - u0) / vu);
    else if (vu < 0.0f) tmax = fminf(tmax, -u0 / vu);
    int te = (int)floorf(tmax) + 3;        // count of steps to examine
    te = max(1, min(te, MAX_S));
    tend[tid] = te;
  }
  __syncthreads();

  const int wid  = tid >> 6;
  const int lane = tid & 63;
  const int half = lane >> 5;              // 0 = fwd, 1 = bwd
  const int sl   = lane & 31;

  float acc = 0.0f;
  for (int k = 0; k < 16; ++k) {
    const int e = wid * 16 + k;
    const int c = e * 2 + half;
    const float x0  = prm[c][0], y0  = prm[c][1];
    const float vx  = prm[c][2], vy  = prm[c][3];
    const float xlo = prm[c][4], xhi = prm[c][5];
    const float ylo = prm[c][6], yhi = prm[c][7];
    const float shw = prm[c][8];
    const float vu = ax ? vx : vy;
    const float u0 = ax ? x0 : y0;
    const int te    = tend[c];
    const int teMax = max(tend[e * 2], tend[e * 2 + 1]);

    for (int t0 = 0; t0 < teMax; t0 += 32) {
      const int t = t0 + sl;
      const float tf = (float)t;
      // exact ref rounding: (t*v) rounded, then + p0 rounded (no fma)
      const float xs = __fadd_rn(__fmul_rn(tf, vx), x0);
      const float ys = __fadd_rn(__fmul_rn(tf, vy), y0);
      const float u  = ax ? xs : ys;
      const float fu = floorf(u);
      bool valid = (t < te) &&
                   (xs <= xhi) && (xs >= xlo) && (ys <= yhi) && (ys >= ylo) &&
                   (u <= (float)(DIM - 1)) && (u >= 0.0f);
      bool keep;
      if (t == 0) {
        keep = valid;
      } else {
        // prev floor(u): identical float expression as step t-1
        const float up = __fadd_rn(__fmul_rn(tf - 1.0f, vu), u0);
        keep = valid && (fu != floorf(up));
      }
      if (!keep) continue;

      const float X0 = floorf(xs), Y0 = floorf(ys);
      const float wx1 = xs - X0, wy1 = ys - Y0;
      const float wx0 = 1.0f - wx1, wy0 = 1.0f - wy1;
      const int ix0 = (int)X0, iy0 = (int)Y0;     // in [-1, 99]
      const int xi0 = max(ix0, 0), xi1 = min(ix0 + 1, DIM - 1);
      const int yi0 = max(iy0, 0), yi1 = min(iy0 + 1, DIM - 1);
      const float g00 = (float)smask[yi0 * DIM + xi0];
      const float g01 = (float)smask[yi1 * DIM + xi0];
      const float g10 = (float)smask[yi0 * DIM + xi1];
      const float g11 = (float)smask[yi1 * DIM + xi1];
      const float val = wx0 * (wy0 * g00 + wy1 * g01) +
                        wx1 * (wy0 * g10 + wy1 * g11);
      acc = fmaf(shw, val, acc);           // sign*0.5/255*val
    }
  }

  // ---- block reduce (4 waves) ----
  #pragma unroll
  for (int o = 32; o > 0; o >>= 1) acc += __shfl_xor(acc, o, 64);
  if ((tid & 63) == 0) red[tid >> 6] = acc;
  __syncthreads();
  if (tid == 0) {
    const float s = red[0] + red[1] + red[2] + red[3];
    ws[bid] = fabsf(s);
  }
}

// ---------------------------------------------------------------------------
// Kernel 2: per-batch areas + final IoU. One wave per batch.
// ---------------------------------------------------------------------------
__device__ __forceinline__ float wave_area(const float* P, int b, int v) {
  const float x0 = P[(size_t)(b * NV + v) * 2 + 0];
  const float y0 = P[(size_t)(b * NV + v) * 2 + 1];
  const int vn = (v + 1) & (NV - 1);
  const float x1 = P[(size_t)(b * NV + vn) * 2 + 0];
  const float y1 = P[(size_t)(b * NV + vn) * 2 + 1];
  float ym = y0;
  #pragma unroll
  for (int o = 32; o > 0; o >>= 1) ym = fmaxf(ym, __shfl_xor(ym, o, 64));
  float term = (x1 - x0) * (ym - (y1 + y0) * 0.5f);
  #pragma unroll
  for (int o = 32; o > 0; o >>= 1) term += __shfl_xor(term, o, 64);
  return fabsf(term);
}

__global__ __launch_bounds__(64) void diffiou_finalize(
    const float* __restrict__ poly, const float* __restrict__ gt,
    const float* __restrict__ ws, float* __restrict__ out) {
  const int b = blockIdx.x;
  const int v = threadIdx.x;
  const float pa = wave_area(poly, b, v);
  const float ga = wave_area(gt, b, v);
  if (v == 0) {
    const float ia = 0.25f * (ws[b * 4 + 0] + ws[b * 4 + 1] +
                              ws[b * 4 + 2] + ws[b * 4 + 3]);
    out[b] = ia / (pa + ga - ia);
  }
}

// ---------------------------------------------------------------------------
extern "C" void kernel_launch(void* const* d_in, const int* in_sizes, int n_in,
                              void* d_out, int out_size, void* d_ws, size_t ws_size,
                              hipStream_t stream) {
  const float* poly    = (const float*)d_in[0];
  const float* gt      = (const float*)d_in[1];
  const float* gt_mask = (const float*)d_in[2];
  float* out = (float*)d_out;
  float* ws  = (float*)d_ws;   // 2048 floats: |s| per (batch, direction)

  hipLaunchKernelGGL(diffiou_intersect, dim3(BS * 4), dim3(256), 0, stream,
                     poly, gt_mask, ws);
  hipLaunchKernelGGL(diffiou_finalize, dim3(BS), dim3(64), 0, stream,
                     poly, gt, ws, out);
}

// Round 5
// 42.667 us; speedup vs baseline: 2.4309x; 1.0999x over previous
//
#include <hip/hip_runtime.h>
#include <math.h>

#define DIM   100
#define NV    64
#define BS    512

// ---------------------------------------------------------------------------
// Kernel 1: one block per (batch, direction m). Mask slice as u8 in LDS
// (10 KB; total ~14.9 KB -> 8 blocks/CU; 8*256 = 2048 = grid, whole grid
// co-resident). Per combo (edge x fwd/bwd) we binary-search the exact last
// valid step T (validity is contiguous from t=0: every condition is a
// float-monotone function of t compared to a constant; bit-identical exprs).
// Work is then compacted into a block-shared chunk table (32 steps/chunk);
// the 8 32-lane groups pull chunks strided -> near-perfect wave balance.
// keep = (t<=T) && (t==0 || floor(u)!=floor(u_prev)).
// ---------------------------------------------------------------------------
__global__ __launch_bounds__(256, 8) void diffiou_intersect(
    const float* __restrict__ poly, const float* __restrict__ gt_mask,
    float* __restrict__ ws) {
  __shared__ unsigned char smask[DIM * DIM];   // 10000 B
  __shared__ float prm[128][5];                // x0,y0,vx,vy,shw (2560 B)
  __shared__ int   Tarr[128];                  // exact last valid t (512 B)
  __shared__ unsigned short chunkTab[128 * 7]; // (c<<3)|k  (1792 B)
  __shared__ int   wsum[2];
  __shared__ int   totalChunks;
  __shared__ float red[4];

  const int bid = blockIdx.x;
  const int b   = bid >> 2;
  const int m   = bid & 3;
  const bool ax = (m < 2);                 // DIRECTIONS = x,x,y,y
  const int tid = threadIdx.x;

  // ---- stage mask slice into LDS, fp32 -> u8 (x255, RNE) ----
  {
    const float4* src = reinterpret_cast<const float4*>(
        gt_mask + (size_t)(b * 4 + m) * (DIM * DIM));
    for (int j = tid; j < DIM * DIM / 4; j += 256) {
      const float4 v = src[j];
      uchar4 c;
      c.x = (unsigned char)__float2int_rn(v.x * 255.0f);
      c.y = (unsigned char)__float2int_rn(v.y * 255.0f);
      c.z = (unsigned char)__float2int_rn(v.z * 255.0f);
      c.w = (unsigned char)__float2int_rn(v.w * 255.0f);
      *reinterpret_cast<uchar4*>(&smask[j * 4]) = c;
    }
  }

  // ---- per-combo setup: params + exact T + chunk count ----
  int ncv = 0;
  if (tid < 128) {
    const int e  = tid >> 1;
    const int fb = tid & 1;
    const float* pb = poly + (size_t)b * NV * 2;
    const float ex0 = pb[e * 2 + 0], ey0 = pb[e * 2 + 1];
    const int   en  = (e + 1) & (NV - 1);
    const float ex1 = pb[en * 2 + 0], ey1 = pb[en * 2 + 1];
    const float sign = (ax ? (ex1 > ex0) : (ey1 > ey0)) ? 1.0f : -1.0f;
    const float x0 = fb ? ex1 : ex0, y0 = fb ? ey1 : ey0;
    const float x1 = fb ? ex0 : ex1, y1 = fb ? ey0 : ey1;
    float vx = (x1 - x0) + 1e-6f;
    float vy = (y1 - y0) + 1e-6f;
    const float n = __fsqrt_rn(__fadd_rn(__fmul_rn(vx, vx), __fmul_rn(vy, vy)));
    vx = __fdiv_rn(vx, n);
    vy = __fdiv_rn(vy, n);
    // bbox with tolerances; fold u-bound [0,99] into the axis coord (exact:
    // (x<=a && x<=b) == (x<=min(a,b)))
    float xlo = fminf(x0, x1) - 0.001f, xhi = fmaxf(x0, x1) + 0.001f;
    float ylo = fminf(y0, y1) - 0.001f, yhi = fmaxf(y0, y1) + 0.001f;
    if (ax) { xlo = fmaxf(xlo, 0.0f); xhi = fminf(xhi, (float)(DIM - 1)); }
    else    { ylo = fmaxf(ylo, 0.0f); yhi = fminf(yhi, (float)(DIM - 1)); }

    // binary search largest valid t in [0,200]; valid(0) always true
    // (x0,y0 in [0,99) and inside their own bbox).
    #define VALID_AT(tt, out) {                                   \
      const float tf_ = (float)(tt);                              \
      const float xs_ = __fadd_rn(__fmul_rn(tf_, vx), x0);        \
      const float ys_ = __fadd_rn(__fmul_rn(tf_, vy), y0);        \
      out = (xs_ <= xhi) && (xs_ >= xlo) &&                       \
            (ys_ <= yhi) && (ys_ >= ylo);                         \
    }
    int T;
    bool v200; VALID_AT(200, v200);
    if (v200) { T = 200; }
    else {
      int lo = 0, hi = 200;
      #pragma unroll
      for (int it = 0; it < 8; ++it) {
        const int mid = (lo + hi) >> 1;
        bool vm; VALID_AT(mid, vm);
        if (vm) lo = mid; else hi = mid;
      }
      T = lo;
    }
    #undef VALID_AT

    prm[tid][0] = x0;  prm[tid][1] = y0;
    prm[tid][2] = vx;  prm[tid][3] = vy;
    prm[tid][4] = sign * (0.5f / 255.0f);
    Tarr[tid] = T;
    ncv = (T >> 5) + 1;                    // chunks of 32 covering [0,T]
  }

  // ---- prefix scan of chunk counts (2 waves), scatter chunk table ----
  int v = ncv;
  #pragma unroll
  for (int i = 1; i < 64; i <<= 1) {
    const int w = __shfl_up(v, i, 64);
    if ((tid & 63) >= i) v += w;
  }
  if (((tid & 63) == 63) && (tid < 128)) wsum[tid >> 6] = v;
  __syncthreads();
  if ((tid >= 64) && (tid < 128)) v += wsum[0];
  if (tid < 128) {
    const int start = v - ncv;
    for (int k = 0; k < ncv; ++k)
      chunkTab[start + k] = (unsigned short)((tid << 3) | k);
    if (tid == 127) totalChunks = v;
  }
  __syncthreads();

  // ---- main loop: 8 groups of 32 lanes pull chunks strided ----
  const int grp = tid >> 5;
  const int sl  = tid & 31;
  const int total = totalChunks;
  float acc = 0.0f;

  for (int g = grp; g < total; g += 8) {
    const int ent = chunkTab[g];
    const int c   = ent >> 3;
    const int t0  = (ent & 7) << 5;
    const float x0 = prm[c][0], y0 = prm[c][1];
    const float vx = prm[c][2], vy = prm[c][3];
    const float shw = prm[c][4];
    const int   T   = Tarr[c];
    const float vu = ax ? vx : vy;
    const float u0 = ax ? x0 : y0;

    const int t = t0 + sl;
    const float tf = (float)t;
    const float xs = __fadd_rn(__fmul_rn(tf, vx), x0);
    const float ys = __fadd_rn(__fmul_rn(tf, vy), y0);
    const float X0 = floorf(xs), Y0 = floorf(ys);
    const float fu = ax ? X0 : Y0;         // == floor(u), reused
    const float up = __fadd_rn(__fmul_rn(tf - 1.0f, vu), u0);
    const float fup = floorf(up);
    const bool keep = (t <= T) && ((t == 0) || (fu != fup));
    if (keep) {
      // valid samples have both coords in [-0.001, 99.002] -> one-sided clamps
      const float wx1 = xs - X0, wy1 = ys - Y0;
      const float wx0 = 1.0f - wx1, wy0 = 1.0f - wy1;
      const int ix0 = (int)X0, iy0 = (int)Y0;      // in [-1, 99]
      const int xi0 = max(ix0, 0), xi1 = min(ix0 + 1, DIM - 1);
      const int yi0 = max(iy0, 0), yi1 = min(iy0 + 1, DIM - 1);
      const float g00 = (float)smask[yi0 * DIM + xi0];
      const float g01 = (float)smask[yi1 * DIM + xi0];
      const float g10 = (float)smask[yi0 * DIM + xi1];
      const float g11 = (float)smask[yi1 * DIM + xi1];
      const float val = wx0 * (wy0 * g00 + wy1 * g01) +
                        wx1 * (wy0 * g10 + wy1 * g11);
      acc = fmaf(shw, val, acc);           // sign*0.5/255*val
    }
  }

  // ---- block reduce (4 waves) ----
  #pragma unroll
  for (int o = 32; o > 0; o >>= 1) acc += __shfl_xor(acc, o, 64);
  if ((tid & 63) == 0) red[tid >> 6] = acc;
  __syncthreads();
  if (tid == 0) {
    const float s = red[0] + red[1] + red[2] + red[3];
    ws[bid] = fabsf(s);
  }
}

// ---------------------------------------------------------------------------
// Kernel 2: per-batch areas + final IoU. One wave per batch.
// ---------------------------------------------------------------------------
__device__ __forceinline__ float wave_area(const float* P, int b, int v) {
  const float x0 = P[(size_t)(b * NV + v) * 2 + 0];
  const float y0 = P[(size_t)(b * NV + v) * 2 + 1];
  const int vn = (v + 1) & (NV - 1);
  const float x1 = P[(size_t)(b * NV + vn) * 2 + 0];
  const float y1 = P[(size_t)(b * NV + vn) * 2 + 1];
  float ym = y0;
  #pragma unroll
  for (int o = 32; o > 0; o >>= 1) ym = fmaxf(ym, __shfl_xor(ym, o, 64));
  float term = (x1 - x0) * (ym - (y1 + y0) * 0.5f);
  #pragma unroll
  for (int o = 32; o > 0; o >>= 1) term += __shfl_xor(term, o, 64);
  return fabsf(term);
}

__global__ __launch_bounds__(64) void diffiou_finalize(
    const float* __restrict__ poly, const float* __restrict__ gt,
    const float* __restrict__ ws, float* __restrict__ out) {
  const int b = blockIdx.x;
  const int v = threadIdx.x;
  const float pa = wave_area(poly, b, v);
  const float ga = wave_area(gt, b, v);
  if (v == 0) {
    const float ia = 0.25f * (ws[b * 4 + 0] + ws[b * 4 + 1] +
                              ws[b * 4 + 2] + ws[b * 4 + 3]);
    out[b] = ia / (pa + ga - ia);
  }
}

// ---------------------------------------------------------------------------
extern "C" void kernel_launch(void* const* d_in, const int* in_sizes, int n_in,
                              void* d_out, int out_size, void* d_ws, size_t ws_size,
                              hipStream_t stream) {
  const float* poly    = (const float*)d_in[0];
  const float* gt      = (const float*)d_in[1];
  const float* gt_mask = (const float*)d_in[2];
  float* out = (float*)d_out;
  float* ws  = (float*)d_ws;   // 2048 floats: |s| per (batch, direction)

  hipLaunchKernelGGL(diffiou_intersect, dim3(BS * 4), dim3(256), 0, stream,
                     poly, gt_mask, ws);
  hipLaunchKernelGGL(diffiou_finalize, dim3(BS), dim3(64), 0, stream,
                     poly, gt, ws, out);
}

// Round 6
// 38.082 us; speedup vs baseline: 2.7236x; 1.1204x over previous
//
#include <hip/hip_runtime.h>
#include <math.h>

#define DIM   100
#define NV    64
#define BS    512
#define MAXCH 2432   // >= 128 combos * 18 chunks + 35 sentinel slots

// ---------------------------------------------------------------------------
// Kernel 1: one block per (batch, direction m). Mask as u8 in LDS (10 KB).
// Per combo (edge x fwd/bwd): exact last valid step T via 8-step binary
// search (validity contiguous from t=0; bit-identical float exprs). Work
// compacted into 8-step chunks (<=18/combo since T <= bbox diag <= 141);
// each 32-lane group processes 4 chunks/iter (lane = slot*8 + step), pulls
// from the pool strided, 2 chunks-quads in flight (ILP x2). Sentinel pad
// entries (k=31 -> t>=248 > Tf) make all reads safe, body branchless.
// keep = (tf<=Tf) && (t==0 || floor(u)!=floor(u_prev)).  Total LDS ~19 KB
// -> 8 blocks/CU, 2048-block grid fully co-resident.
// ---------------------------------------------------------------------------
__global__ __launch_bounds__(256, 8) void diffiou_intersect(
    const float* __restrict__ poly, const float* __restrict__ gt_mask,
    float* __restrict__ ws) {
  __shared__ unsigned char smask[DIM * DIM];     // 10000 B
  __shared__ float prm[128][8];                  // 4096 B: x0,y0,vx,vy,shw,Tf,vu,u0
  __shared__ unsigned short chunkTab[MAXCH];     // 4864 B
  __shared__ int   wsum[2];
  __shared__ int   totalChunks;
  __shared__ float red[4];

  const int bid = blockIdx.x;
  const int b   = bid >> 2;
  const int m   = bid & 3;
  const bool ax = (m < 2);                 // DIRECTIONS = x,x,y,y
  const int tid = threadIdx.x;

  // ---- phase 1: stage mask (fp32 -> u8), prefill sentinel table ----
  {
    const float4* src = reinterpret_cast<const float4*>(
        gt_mask + (size_t)(b * 4 + m) * (DIM * DIM));
    for (int j = tid; j < DIM * DIM / 4; j += 256) {
      const float4 v = src[j];
      uchar4 c;
      c.x = (unsigned char)__float2int_rn(v.x * 255.0f);
      c.y = (unsigned char)__float2int_rn(v.y * 255.0f);
      c.z = (unsigned char)__float2int_rn(v.z * 255.0f);
      c.w = (unsigned char)__float2int_rn(v.w * 255.0f);
      *reinterpret_cast<uchar4*>(&smask[j * 4]) = c;
    }
    for (int j = tid; j < MAXCH; j += 256) chunkTab[j] = 31;  // c=0,k=31 sentinel
  }

  // ---- per-combo setup ----
  int ncv = 0;
  if (tid < 128) {
    const int e  = tid >> 1;
    const int fb = tid & 1;
    const float* pb = poly + (size_t)b * NV * 2;
    const float ex0 = pb[e * 2 + 0], ey0 = pb[e * 2 + 1];
    const int   en  = (e + 1) & (NV - 1);
    const float ex1 = pb[en * 2 + 0], ey1 = pb[en * 2 + 1];
    const float sign = (ax ? (ex1 > ex0) : (ey1 > ey0)) ? 1.0f : -1.0f;
    const float x0 = fb ? ex1 : ex0, y0 = fb ? ey1 : ey0;
    const float x1 = fb ? ex0 : ex1, y1 = fb ? ey0 : ey1;
    float vx = (x1 - x0) + 1e-6f;
    float vy = (y1 - y0) + 1e-6f;
    const float n = __fsqrt_rn(__fadd_rn(__fmul_rn(vx, vx), __fmul_rn(vy, vy)));
    vx = __fdiv_rn(vx, n);
    vy = __fdiv_rn(vy, n);
    // bbox + tolerances; u-bound [0,99] folded into the axis coord (exact)
    float xlo = fminf(x0, x1) - 0.001f, xhi = fmaxf(x0, x1) + 0.001f;
    float ylo = fminf(y0, y1) - 0.001f, yhi = fmaxf(y0, y1) + 0.001f;
    if (ax) { xlo = fmaxf(xlo, 0.0f); xhi = fminf(xhi, (float)(DIM - 1)); }
    else    { ylo = fmaxf(ylo, 0.0f); yhi = fminf(yhi, (float)(DIM - 1)); }

    #define VALID_AT(tt, out) {                                   \
      const float tf_ = (float)(tt);                              \
      const float xs_ = __fadd_rn(__fmul_rn(tf_, vx), x0);        \
      const float ys_ = __fadd_rn(__fmul_rn(tf_, vy), y0);        \
      out = (xs_ <= xhi) && (xs_ >= xlo) &&                       \
            (ys_ <= yhi) && (ys_ >= ylo);                         \
    }
    int T;
    bool v200; VALID_AT(200, v200);
    if (v200) { T = 200; }
    else {
      int lo = 0, hi = 200;
      #pragma unroll
      for (int it = 0; it < 8; ++it) {
        const int mid = (lo + hi) >> 1;
        bool vm; VALID_AT(mid, vm);
        if (vm) lo = mid; else hi = mid;
      }
      T = lo;
    }
    #undef VALID_AT
    T = min(T, 143);                       // math bound ~141; table safety

    prm[tid][0] = x0;  prm[tid][1] = y0;
    prm[tid][2] = vx;  prm[tid][3] = vy;
    prm[tid][4] = sign * (0.5f / 255.0f);
    prm[tid][5] = (float)T;
    prm[tid][6] = ax ? vx : vy;
    prm[tid][7] = ax ? x0 : y0;
    ncv = (T >> 3) + 1;                    // 8-step chunks covering [0,T]
  }

  // ---- prefix scan (2 waves) + scatter chunk table ----
  int v = ncv;
  #pragma unroll
  for (int i = 1; i < 64; i <<= 1) {
    const int w = __shfl_up(v, i, 64);
    if ((tid & 63) >= i) v += w;
  }
  if (((tid & 63) == 63) && (tid < 128)) wsum[tid >> 6] = v;
  __syncthreads();
  if ((tid >= 64) && (tid < 128)) v += wsum[0];
  if (tid < 128) {
    const int start = v - ncv;
    for (int k = 0; k < ncv; ++k)
      chunkTab[start + k] = (unsigned short)((tid << 5) | k);
    if (tid == 127) totalChunks = v;
  }
  __syncthreads();

  // ---- main loop: 8 groups x 4 chunks/iter, ILP x2 ----
  const int grp = tid >> 5;
  const int sub = (tid >> 3) & 3;          // chunk slot within group
  const int st  = tid & 7;                 // step within chunk
  const int totE = totalChunks;
  float acc = 0.0f;

  for (int j = grp; j * 4 < totE; j += 16) {
    const int eA = chunkTab[j * 4 + sub];
    const int eB = chunkTab[j * 4 + sub + 32];
    const int cA = eA >> 5, cB = eB >> 5;
    const int tA = ((eA & 31) << 3) | st;
    const int tB = ((eB & 31) << 3) | st;
    const float4 pA = *reinterpret_cast<const float4*>(&prm[cA][0]);
    const float4 qA = *reinterpret_cast<const float4*>(&prm[cA][4]);
    const float4 pB = *reinterpret_cast<const float4*>(&prm[cB][0]);
    const float4 qB = *reinterpret_cast<const float4*>(&prm[cB][4]);

    #define SAMPLE(p, q, t) {                                              \
      const float tf = (float)(t);                                         \
      const float xs = __fadd_rn(__fmul_rn(tf, p.z), p.x);                 \
      const float ys = __fadd_rn(__fmul_rn(tf, p.w), p.y);                 \
      const float X0 = floorf(xs), Y0 = floorf(ys);                        \
      const float fu = ax ? X0 : Y0;                                       \
      const float up = __fadd_rn(__fmul_rn(tf - 1.0f, q.z), q.w);          \
      const bool keep = (tf <= q.y) && (((t) == 0) || (fu != floorf(up))); \
      const float wx1 = xs - X0, wy1 = ys - Y0;                            \
      const float wx0 = 1.0f - wx1, wy0 = 1.0f - wy1;                      \
      const int ix0 = (int)X0, iy0 = (int)Y0;                              \
      const int xi0 = min(max(ix0, 0), DIM - 1);                           \
      const int xi1 = min(max(ix0 + 1, 0), DIM - 1);                       \
      const int yi0 = min(max(iy0, 0), DIM - 1);                           \
      const int yi1 = min(max(iy0 + 1, 0), DIM - 1);                       \
      const int a00 = yi0 * DIM + xi0, a01 = yi1 * DIM + xi0;              \
      const int xoff = xi1 - xi0;                                          \
      const float g00 = (float)smask[a00];                                 \
      const float g01 = (float)smask[a01];                                 \
      const float g10 = (float)smask[a00 + xoff];                          \
      const float g11 = (float)smask[a01 + xoff];                          \
      const float val = wx0 * (wy0 * g00 + wy1 * g01) +                    \
                        wx1 * (wy0 * g10 + wy1 * g11);                     \
      acc = fmaf(keep ? q.x : 0.0f, val, acc);                             \
    }
    SAMPLE(pA, qA, tA);
    SAMPLE(pB, qB, tB);
    #undef SAMPLE
  }

  // ---- block reduce (4 waves) ----
  #pragma unroll
  for (int o = 32; o > 0; o >>= 1) acc += __shfl_xor(acc, o, 64);
  if ((tid & 63) == 0) red[tid >> 6] = acc;
  __syncthreads();
  if (tid == 0) {
    const float s = red[0] + red[1] + red[2] + red[3];
    ws[bid] = fabsf(s);
  }
}

// ---------------------------------------------------------------------------
// Kernel 2: per-batch areas + final IoU. One wave per batch.
// ---------------------------------------------------------------------------
__device__ __forceinline__ float wave_area(const float* P, int b, int v) {
  const float x0 = P[(size_t)(b * NV + v) * 2 + 0];
  const float y0 = P[(size_t)(b * NV + v) * 2 + 1];
  const int vn = (v + 1) & (NV - 1);
  const float x1 = P[(size_t)(b * NV + vn) * 2 + 0];
  const float y1 = P[(size_t)(b * NV + vn) * 2 + 1];
  float ym = y0;
  #pragma unroll
  for (int o = 32; o > 0; o >>= 1) ym = fmaxf(ym, __shfl_xor(ym, o, 64));
  float term = (x1 - x0) * (ym - (y1 + y0) * 0.5f);
  #pragma unroll
  for (int o = 32; o > 0; o >>= 1) term += __shfl_xor(term, o, 64);
  return fabsf(term);
}

__global__ __launch_bounds__(64) void diffiou_finalize(
    const float* __restrict__ poly, const float* __restrict__ gt,
    const float* __restrict__ ws, float* __restrict__ out) {
  const int b = blockIdx.x;
  const int v = threadIdx.x;
  const float pa = wave_area(poly, b, v);
  const float ga = wave_area(gt, b, v);
  if (v == 0) {
    const float ia = 0.25f * (ws[b * 4 + 0] + ws[b * 4 + 1] +
                              ws[b * 4 + 2] + ws[b * 4 + 3]);
    out[b] = ia / (pa + ga - ia);
  }
}

// ---------------------------------------------------------------------------
extern "C" void kernel_launch(void* const* d_in, const int* in_sizes, int n_in,
                              void* d_out, int out_size, void* d_ws, size_t ws_size,
                              hipStream_t stream) {
  const float* poly    = (const float*)d_in[0];
  const float* gt      = (const float*)d_in[1];
  const float* gt_mask = (const float*)d_in[2];
  float* out = (float*)d_out;
  float* ws  = (float*)d_ws;   // 2048 floats: |s| per (batch, direction)

  hipLaunchKernelGGL(diffiou_intersect, dim3(BS * 4), dim3(256), 0, stream,
                     poly, gt_mask, ws);
  hipLaunchKernelGGL(diffiou_finalize, dim3(BS), dim3(64), 0, stream,
                     poly, gt, ws, out);
}

// Round 7
// 34.285 us; speedup vs baseline: 3.0252x; 1.1107x over previous
//
#include <hip/hip_runtime.h>
#include <math.h>

#define DIM   100
#define NV    64
#define BS    512
#define MAXCH 1728   // >= 128 combos * 13 chunks + 36 overrun slots

// ---------------------------------------------------------------------------
// Kernel 1: one block per (batch, direction m). Mask as u8 in LDS (10 KB).
// Ref keeps exactly one sample per integer u-cell crossed (u monotone in t).
// Per combo: binary-search exact last valid step T (bit-identical exprs),
// K = |floor(u(T)) - floor(u(0))| -> kept samples k=0..K. For each k, the
// kept t is the minimal integer with floor(u(t)) == cell_k; we estimate
// t = ceil((D+k)*B - 5e-3) and fix up with ONE check of the bit-exact
// floor(u(t)) expression (biased-low estimate => only the +1 correction is
// needed; exact except ~1e-5-rare rounding windows, error budget ~1e-4).
// Work pool = 8-kept-sample chunks, pulled strided by 8 32-lane groups,
// ILP x2. Pad lanes: weight 0, t clamped to [0,300], full index clamps ->
// NaN/garbage-proof. LDS ~17.6 KB -> 8 blocks/CU, 2048-block grid fully
// co-resident.
// ---------------------------------------------------------------------------
__global__ __launch_bounds__(256, 8) void diffiou_intersect(
    const float* __restrict__ poly, const float* __restrict__ gt_mask,
    float* __restrict__ ws) {
  __shared__ unsigned char smask[DIM * DIM];     // 10000 B
  __shared__ float prm[128][8];                  // 4096 B: x0,y0,vx,vy,shw,Kf,B,A
  __shared__ unsigned short chunkTab[MAXCH];     // 3456 B
  __shared__ int   wsum[2];
  __shared__ int   totalChunks;
  __shared__ float red[4];

  const int bid = blockIdx.x;
  const int b   = bid >> 2;
  const int m   = bid & 3;
  const bool ax = (m < 2);                 // DIRECTIONS = x,x,y,y
  const int tid = threadIdx.x;

  // ---- phase 1: stage mask (fp32 -> u8), prefill sentinel table ----
  {
    const float4* src = reinterpret_cast<const float4*>(
        gt_mask + (size_t)(b * 4 + m) * (DIM * DIM));
    for (int j = tid; j < DIM * DIM / 4; j += 256) {
      const float4 v = src[j];
      uchar4 c;
      c.x = (unsigned char)__float2int_rn(v.x * 255.0f);
      c.y = (unsigned char)__float2int_rn(v.y * 255.0f);
      c.z = (unsigned char)__float2int_rn(v.z * 255.0f);
      c.w = (unsigned char)__float2int_rn(v.w * 255.0f);
      *reinterpret_cast<uchar4*>(&smask[j * 4]) = c;
    }
    for (int j = tid; j < MAXCH; j += 256) chunkTab[j] = 15;  // c=0,chk=15
  }

  // ---- per-combo setup ----
  int ncv = 0;
  if (tid < 128) {
    const int e  = tid >> 1;
    const int fb = tid & 1;
    const float* pb = poly + (size_t)b * NV * 2;
    const float ex0 = pb[e * 2 + 0], ey0 = pb[e * 2 + 1];
    const int   en  = (e + 1) & (NV - 1);
    const float ex1 = pb[en * 2 + 0], ey1 = pb[en * 2 + 1];
    const float sign = (ax ? (ex1 > ex0) : (ey1 > ey0)) ? 1.0f : -1.0f;
    const float x0 = fb ? ex1 : ex0, y0 = fb ? ey1 : ey0;
    const float x1 = fb ? ex0 : ex1, y1 = fb ? ey0 : ey1;
    float vx = (x1 - x0) + 1e-6f;
    float vy = (y1 - y0) + 1e-6f;
    const float n = __fsqrt_rn(__fadd_rn(__fmul_rn(vx, vx), __fmul_rn(vy, vy)));
    vx = __fdiv_rn(vx, n);
    vy = __fdiv_rn(vy, n);
    // bbox + tolerances; u-bound [0,99] folded into the axis coord (exact)
    float xlo = fminf(x0, x1) - 0.001f, xhi = fmaxf(x0, x1) + 0.001f;
    float ylo = fminf(y0, y1) - 0.001f, yhi = fmaxf(y0, y1) + 0.001f;
    if (ax) { xlo = fmaxf(xlo, 0.0f); xhi = fminf(xhi, (float)(DIM - 1)); }
    else    { ylo = fmaxf(ylo, 0.0f); yhi = fminf(yhi, (float)(DIM - 1)); }

    #define VALID_AT(tt, out) {                                   \
      const float tf_ = (float)(tt);                              \
      const float xs_ = __fadd_rn(__fmul_rn(tf_, vx), x0);        \
      const float ys_ = __fadd_rn(__fmul_rn(tf_, vy), y0);        \
      out = (xs_ <= xhi) && (xs_ >= xlo) &&                       \
            (ys_ <= yhi) && (ys_ >= ylo);                         \
    }
    int T;
    bool v200; VALID_AT(200, v200);
    if (v200) { T = 200; }
    else {
      int lo = 0, hi = 200;
      #pragma unroll
      for (int it = 0; it < 8; ++it) {
        const int mid = (lo + hi) >> 1;
        bool vm; VALID_AT(mid, vm);
        if (vm) lo = mid; else hi = mid;
      }
      T = lo;
    }
    #undef VALID_AT

    // kept-sample machinery
    const float vu  = ax ? vx : vy;
    const float u0  = ax ? x0 : y0;
    const float fu0 = floorf(u0);
    const float uT  = __fadd_rn(__fmul_rn((float)T, vu), u0);
    int K = abs((int)floorf(uT) - (int)fu0);
    K = min(K, 99);
    const float B = __fdiv_rn(1.0f, fabsf(vu));            // may be +inf
    const float D = (vu > 0.0f) ? (fu0 - u0) : (u0 - fu0 - 1.0f);
    prm[tid][0] = x0;  prm[tid][1] = y0;
    prm[tid][2] = vx;  prm[tid][3] = vy;
    prm[tid][4] = sign * (0.5f / 255.0f);
    prm[tid][5] = (float)K;
    prm[tid][6] = B;
    prm[tid][7] = D * B;                                   // A (<= 0)
    ncv = (K >> 3) + 1;                                    // 8-kept chunks
  }

  // ---- prefix scan (2 waves) + scatter chunk table ----
  int v = ncv;
  #pragma unroll
  for (int i = 1; i < 64; i <<= 1) {
    const int w = __shfl_up(v, i, 64);
    if ((tid & 63) >= i) v += w;
  }
  if (((tid & 63) == 63) && (tid < 128)) wsum[tid >> 6] = v;
  __syncthreads();
  if ((tid >= 64) && (tid < 128)) v += wsum[0];
  if (tid < 128) {
    const int start = v - ncv;
    for (int k = 0; k < ncv; ++k)
      chunkTab[start + k] = (unsigned short)((tid << 4) | k);
    if (tid == 127) totalChunks = v;
  }
  __syncthreads();

  // ---- main loop: 8 groups x 4 chunks/iter, ILP x2, all samples kept ----
  const int grp = tid >> 5;
  const int sub = (tid >> 3) & 3;          // chunk slot within group
  const int st  = tid & 7;                 // kept-sample index within chunk
  const int totE = totalChunks;
  float acc = 0.0f;

  for (int j = grp; j * 4 < totE; j += 16) {
    const int eA = chunkTab[j * 4 + sub];
    const int eB = chunkTab[j * 4 + sub + 32];
    const int cA = eA >> 4, cB = eB >> 4;
    const int kA = (((eA & 15) << 3) | st);
    const int kB = (((eB & 15) << 3) | st);
    const float4 pA = *reinterpret_cast<const float4*>(&prm[cA][0]);
    const float4 qA = *reinterpret_cast<const float4*>(&prm[cA][4]);
    const float4 pB = *reinterpret_cast<const float4*>(&prm[cB][0]);
    const float4 qB = *reinterpret_cast<const float4*>(&prm[cB][4]);

    // p = {x0,y0,vx,vy}; q = {shw, Kf, B, A}
    #define SAMPLE(p, q, kidx) {                                           \
      const float kf  = (float)(kidx);                                     \
      const float vu  = ax ? p.z : p.w;                                    \
      const float u0  = ax ? p.x : p.y;                                    \
      const float fu0 = floorf(u0);                                        \
      const float ck  = fu0 + ((vu > 0.0f) ? kf : -kf);                    \
      const float te  = ceilf(fmaf(kf, q.z, q.w) - 0.005f);                \
      const float u1  = __fadd_rn(__fmul_rn(te, vu), u0);                  \
      float t = (floorf(u1) == ck) ? te : (te + 1.0f);                     \
      t = fminf(fmaxf(t, 0.0f), 300.0f);                                   \
      const float xs = __fadd_rn(__fmul_rn(t, p.z), p.x);                  \
      const float ys = __fadd_rn(__fmul_rn(t, p.w), p.y);                  \
      const float X0 = floorf(xs), Y0 = floorf(ys);                        \
      const float wx1 = xs - X0, wy1 = ys - Y0;                            \
      const float wx0 = 1.0f - wx1, wy0 = 1.0f - wy1;                      \
      const int ix0 = (int)X0, iy0 = (int)Y0;                              \
      const int xi0 = min(max(ix0, 0), DIM - 1);                           \
      const int xi1 = min(max(ix0 + 1, 0), DIM - 1);                       \
      const int yi0 = min(max(iy0, 0), DIM - 1);                           \
      const int yi1 = min(max(iy0 + 1, 0), DIM - 1);                       \
      const int a00 = yi0 * DIM + xi0, a01 = yi1 * DIM + xi0;              \
      const int xoff = xi1 - xi0;                                          \
      const float g00 = (float)smask[a00];                                 \
      const float g01 = (float)smask[a01];                                 \
      const float g10 = (float)smask[a00 + xoff];                          \
      const float g11 = (float)smask[a01 + xoff];                          \
      const float val = wx0 * (wy0 * g00 + wy1 * g01) +                    \
                        wx1 * (wy0 * g10 + wy1 * g11);                     \
      const float w = (kf <= q.y) ? q.x : 0.0f;                            \
      acc = fmaf(w, val, acc);                                             \
    }
    SAMPLE(pA, qA, kA);
    SAMPLE(pB, qB, kB);
    #undef SAMPLE
  }

  // ---- block reduce (4 waves) ----
  #pragma unroll
  for (int o = 32; o > 0; o >>= 1) acc += __shfl_xor(acc, o, 64);
  if ((tid & 63) == 0) red[tid >> 6] = acc;
  __syncthreads();
  if (tid == 0) {
    const float s = red[0] + red[1] + red[2] + red[3];
    ws[bid] = fabsf(s);
  }
}

// ---------------------------------------------------------------------------
// Kernel 2: per-batch areas + final IoU. One wave per batch.
// ---------------------------------------------------------------------------
__device__ __forceinline__ float wave_area(const float* P, int b, int v) {
  const float x0 = P[(size_t)(b * NV + v) * 2 + 0];
  const float y0 = P[(size_t)(b * NV + v) * 2 + 1];
  const int vn = (v + 1) & (NV - 1);
  const float x1 = P[(size_t)(b * NV + vn) * 2 + 0];
  const float y1 = P[(size_t)(b * NV + vn) * 2 + 1];
  float ym = y0;
  #pragma unroll
  for (int o = 32; o > 0; o >>= 1) ym = fmaxf(ym, __shfl_xor(ym, o, 64));
  float term = (x1 - x0) * (ym - (y1 + y0) * 0.5f);
  #pragma unroll
  for (int o = 32; o > 0; o >>= 1) term += __shfl_xor(term, o, 64);
  return fabsf(term);
}

__global__ __launch_bounds__(64) void diffiou_finalize(
    const float* __restrict__ poly, const float* __restrict__ gt,
    const float* __restrict__ ws, float* __restrict__ out) {
  const int b = blockIdx.x;
  const int v = threadIdx.x;
  const float pa = wave_area(poly, b, v);
  const float ga = wave_area(gt, b, v);
  if (v == 0) {
    const float ia = 0.25f * (ws[b * 4 + 0] + ws[b * 4 + 1] +
                              ws[b * 4 + 2] + ws[b * 4 + 3]);
    out[b] = ia / (pa + ga - ia);
  }
}

// ---------------------------------------------------------------------------
extern "C" void kernel_launch(void* const* d_in, const int* in_sizes, int n_in,
                              void* d_out, int out_size, void* d_ws, size_t ws_size,
                              hipStream_t stream) {
  const float* poly    = (const float*)d_in[0];
  const float* gt      = (const float*)d_in[1];
  const float* gt_mask = (const float*)d_in[2];
  float* out = (float*)d_out;
  float* ws  = (float*)d_ws;   // 2048 floats: |s| per (batch, direction)

  hipLaunchKernelGGL(diffiou_intersect, dim3(BS * 4), dim3(256), 0, stream,
                     poly, gt_mask, ws);
  hipLaunchKernelGGL(diffiou_finalize, dim3(BS), dim3(64), 0, stream,
                     poly, gt, ws, out);
}